// Round 11
// baseline (273.980 us; speedup 1.0000x reference)
//
#include <hip/hip_runtime.h>
#include <hip/hip_bf16.h>
#include <math.h>

// KAN 2-layer forward, MI355X (gfx950) — round 11.
//   init_fused   : prep W1 (row-major aug), prep W2 -> W2f fragment-major,
//                  expand x -> F1. (r10, unchanged)
//   kan_gemm1    : F1 @ W1^T + exact-GELU -> h f32. (r8/r10, unchanged, ~46us)
//   kan_gemm2    : REGISTER-ONLY rewrite. 1-wave blocks (64 thr), BM=64 BN=64,
//                  split-K=8, grid 128x4x8 = 4096 waves, no barriers, no
//                  main-loop LDS. Each lane computes ITS OWN A-fragment:
//                  frag(fm,ks) @ lane(lr,lg) = kan_features(H[n0+fm*16+lr]
//                  [kt*8+ks*4+lg]) — one h -> one 8-bf16 feature vector.
//                  B-frags = 1KB/wave coalesced loads from W2f (r10 infra).
//                  Feature VALU co-issues with other waves' MFMA (m114).
//   reduce_split : sum 8 partial slices -> out. (unchanged)
// Lessons kept: no fences/atomics in hot kernels (r8); 4+ indep waves/SIMD
// beat every lockstep pipelining attempt (r5/r7/r9).

typedef __attribute__((ext_vector_type(8))) short bf16x8;   // 8 x bf16
typedef __attribute__((ext_vector_type(4))) float f32x4;

#define TOKENS 8192
#define D_IN   256
#define D_HID  1024

// ---- exact uniform-cubic-B-spline features (closed form) ----
__device__ __forceinline__ void kan_features(float x, float f[8]) {
    f[0] = x * __builtin_amdgcn_rcpf(1.0f + __expf(-x));   // silu via v_rcp
    const float s = (x + 1.0f) * 1.5f + 3.0f;
    const float cf = floorf(s);
    const float u = s - cf;
    const int c = (int)cf;
    const float u2 = u * u, u3 = u2 * u;
    const float k6 = 1.0f / 6.0f;
    const float v3 = u3 * k6;
    const float v2 = (-3.0f * u3 + 3.0f * u2 + 3.0f * u + 1.0f) * k6;
    const float v1 = (3.0f * u3 - 6.0f * u2 + 4.0f) * k6;
    const float w1 = 1.0f - u;
    const float v0 = w1 * w1 * w1 * k6;
    const bool in = (s >= 0.0f) && (s < 9.0f);
#pragma unroll
    for (int j = 0; j < 6; ++j) {
        int d = c - j;
        float bv = (d == 0) ? v3 : (d == 1) ? v2 : (d == 2) ? v1 : (d == 3) ? v0 : 0.0f;
        f[1 + j] = in ? bv : 0.0f;
    }
    f[7] = 0.0f;
}

__device__ __forceinline__ void features_to_bf16(const float f[8], __hip_bfloat16 fb[8]) {
#pragma unroll
    for (int j = 0; j < 8; ++j) fb[j] = __float2bfloat16(f[j]);
}

// ---------------- fused init ----------------
__global__ void init_fused(const float* __restrict__ X, __hip_bfloat16* __restrict__ F,
                           const float* __restrict__ bw1, const float* __restrict__ sw1,
                           const float* __restrict__ sc1, __hip_bfloat16* __restrict__ W1,
                           const float* __restrict__ bw2, const float* __restrict__ sw2,
                           const float* __restrict__ sc2, __hip_bfloat16* __restrict__ W2f) {
    const int b = blockIdx.x;
    if (b < 8192) {                          // expand x: 2M elements
        int idx = b * 256 + threadIdx.x;
        float f[8];
        kan_features(X[idx], f);
        __hip_bfloat16 fb[8];
        features_to_bf16(f, fb);
        *(bf16x8*)&F[(size_t)idx * 8] = *(bf16x8*)fb;
        return;
    }
    const bool w1 = (b < 9216);
    int idx = (w1 ? (b - 8192) : (b - 9216)) * 256 + threadIdx.x;   // < 262144
    const float* bw = w1 ? bw1 : bw2;
    const float* sw = w1 ? sw1 : sw2;
    const float* sc = w1 ? sc1 : sc2;
    float scl = sc[idx];
    __hip_bfloat16 row[8];
    row[0] = __float2bfloat16(bw[idx]);
#pragma unroll
    for (int j = 0; j < 6; ++j)
        row[1 + j] = __float2bfloat16(sw[idx * 6 + j] * scl);
    row[7] = __float2bfloat16(0.0f);
    if (w1) {
        *(bf16x8*)&W1[(size_t)idx * 8] = *(bf16x8*)row;          // row-major aug
    } else {
        // fragment-major: elem (o, k=i*8+j) -> W2f[(k>>5)*8192 + o*32 + (k&31)]
        int o = idx >> 10, i = idx & 1023;
        *(bf16x8*)&W2f[(size_t)(i >> 2) * 8192 + o * 32 + (i & 3) * 8] = *(bf16x8*)row;
    }
}

#define GLL(src, dst) __builtin_amdgcn_global_load_lds(                         \
    (const __attribute__((address_space(1))) void*)(src),                       \
    (__attribute__((address_space(3))) void*)(dst), 16, 0, 0)

// ---------------- GEMM1: H = GELU(F1 @ W1^T), 128x128, BK=64, counted-vmcnt ----
__global__ __launch_bounds__(256, 2)
void kan_gemm1(const __hip_bfloat16* __restrict__ A,
               const __hip_bfloat16* __restrict__ W,
               float* __restrict__ H) {
    constexpr int K = D_IN * 8;            // 2048
    constexpr int NT = K / 64;             // 32 k-tiles
    __shared__ __hip_bfloat16 Al[2][128 * 64];
    __shared__ __hip_bfloat16 Bl[2][128 * 64];

    const int tid = threadIdx.x;
    const int wid = tid >> 6, lane = tid & 63;
    const int wm = wid >> 1, wn = wid & 1;
    const int lr = lane & 15, lg = lane >> 4;
    const int n0 = blockIdx.x * 128, o0 = blockIdx.y * 128;

    int srow[4], sslot[4];
#pragma unroll
    for (int p = 0; p < 4; ++p) {
        int item = tid + p * 256;
        srow[p] = item >> 3;
        sslot[p] = (item & 7) ^ (srow[p] & 7);
    }
    int aoff[2][4], boff[2][4];
#pragma unroll
    for (int ks = 0; ks < 2; ++ks)
#pragma unroll
        for (int f = 0; f < 4; ++f) {
            int ar = wm * 64 + f * 16 + lr;
            int br = wn * 64 + f * 16 + lr;
            aoff[ks][f] = ar * 64 + (((ks * 4 + lg) ^ (ar & 7)) * 8);
            boff[ks][f] = br * 64 + (((ks * 4 + lg) ^ (br & 7)) * 8);
        }

    f32x4 acc[4][4] = {};

#define STG1(buf, kt)                                                           \
    do {                                                                        \
        _Pragma("unroll")                                                       \
        for (int p = 0; p < 4; ++p) {                                           \
            GLL(A + (size_t)(n0 + srow[p]) * K + (kt) * 64 + sslot[p] * 8,      \
                &Al[buf][(tid + p * 256) * 8]);                                 \
            GLL(W + (size_t)(o0 + srow[p]) * K + (kt) * 64 + sslot[p] * 8,      \
                &Bl[buf][(tid + p * 256) * 8]);                                 \
        }                                                                       \
    } while (0)

    STG1(0, 0);
    STG1(1, 1);
    for (int t = 0; t < NT; ++t) {
        const int cur = t & 1;
        asm volatile("s_waitcnt vmcnt(8)" ::: "memory");
        __builtin_amdgcn_s_barrier();
        __builtin_amdgcn_sched_barrier(0);
        __builtin_amdgcn_s_setprio(1);
#pragma unroll
        for (int ks = 0; ks < 2; ++ks) {
            bf16x8 af[4], bfr[4];
#pragma unroll
            for (int f = 0; f < 4; ++f) af[f] = *(const bf16x8*)&Al[cur][aoff[ks][f]];
#pragma unroll
            for (int f = 0; f < 4; ++f) bfr[f] = *(const bf16x8*)&Bl[cur][boff[ks][f]];
#pragma unroll
            for (int fm = 0; fm < 4; ++fm)
#pragma unroll
                for (int fn = 0; fn < 4; ++fn)
                    acc[fm][fn] = __builtin_amdgcn_mfma_f32_16x16x32_bf16(
                        af[fm], bfr[fn], acc[fm][fn], 0, 0, 0);
        }
        __builtin_amdgcn_s_setprio(0);
        asm volatile("s_waitcnt lgkmcnt(0)" ::: "memory");
        __builtin_amdgcn_s_barrier();
        __builtin_amdgcn_sched_barrier(0);
        const int kn = (t + 2 < NT) ? t + 2 : NT - 1;
        STG1(cur, kn);
    }
#undef STG1
#pragma unroll
    for (int fm = 0; fm < 4; ++fm) {
#pragma unroll
        for (int fn = 0; fn < 4; ++fn) {
            int col = o0 + wn * 64 + fn * 16 + lr;
#pragma unroll
            for (int r = 0; r < 4; ++r) {
                int row = n0 + wm * 64 + fm * 16 + lg * 4 + r;
                float v = acc[fm][fn][r];
                H[(size_t)row * D_HID + col] = 0.5f * v * (1.0f + erff(v * 0.70710678118f));
            }
        }
    }
}

// ---------------- GEMM2: register-only, 1 wave/block, no barriers ----------------
// BM=64, BN=64, BK=64 (8 h-cols/tile), split-K=8. grid (128, 4, 8) x 64 thr.
// A-frag(fm,ks) @ lane(lr,lg) = features(H[n0+fm*16+lr][kt*8+ks*4+lg]).
__global__ __launch_bounds__(64, 3)
void kan_gemm2(const float* __restrict__ H,
               const __hip_bfloat16* __restrict__ W2f,
               float* __restrict__ P) {
    constexpr int OUT = D_IN;                   // 256
    const int lane = threadIdx.x;
    const int lr = lane & 15, lg = lane >> 4;
    const int n0 = blockIdx.x * 64;
    const int by = blockIdx.y;                  // 0..3 (out-col block)
    const int ks0 = blockIdx.z * 16, ks1 = ks0 + 16;

    __shared__ float Pl[32 * 64];               // 8KB, epilogue only

    // per-lane H base: row n0+lr (+f*16), col lg (+kt*8 + ks*4)
    const float* hrow = H + (size_t)(n0 + lr) * D_HID + lg;
    // B: fragment-major W2f, wave reads contiguous 1KB per frag
    const __hip_bfloat16* wp = W2f + (size_t)ks0 * 2 * 8192;
    int bcol[4];
#pragma unroll
    for (int f = 0; f < 4; ++f) bcol[f] = (by * 64 + f * 16 + lr) * 32 + lg * 8;

    f32x4 acc[4][4] = {};
    float hA[8], hB[8];

#define LOADH(d, T)                                                             \
    do {                                                                        \
        _Pragma("unroll") for (int f = 0; f < 4; ++f)                           \
        _Pragma("unroll") for (int ks = 0; ks < 2; ++ks)                        \
            d[f * 2 + ks] = hrow[f * 16 * D_HID + (T) * 8 + ks * 4];            \
    } while (0)

    // One k-tile: B loads issue first; h(t+1) next; feature VALU (~900cyc)
    // covers both latencies; MFMA consumes via scoreboard. No barriers.
#define TILE(T, hc, hn, DO)                                                     \
    do {                                                                        \
        bf16x8 bw[2][4];                                                        \
        _Pragma("unroll") for (int ks = 0; ks < 2; ++ks)                        \
        _Pragma("unroll") for (int f = 0; f < 4; ++f)                           \
            bw[ks][f] = *(const bf16x8*)&wp[(size_t)(((T) - ks0) * 2 + ks) * 8192 \
                                             + bcol[f]];                        \
        if (DO) LOADH(hn, (T) + 1);                                             \
        _Pragma("unroll") for (int ks = 0; ks < 2; ++ks) {                      \
            bf16x8 af[4];                                                       \
            _Pragma("unroll") for (int f = 0; f < 4; ++f) {                     \
                float ff[8]; __hip_bfloat16 fb[8];                              \
                kan_features(hc[f * 2 + ks], ff);                               \
                features_to_bf16(ff, fb);                                       \
                af[f] = *(bf16x8*)fb;                                           \
            }                                                                   \
            _Pragma("unroll") for (int fm = 0; fm < 4; ++fm)                    \
            _Pragma("unroll") for (int fn = 0; fn < 4; ++fn)                    \
                acc[fm][fn] = __builtin_amdgcn_mfma_f32_16x16x32_bf16(          \
                    af[fm], bw[ks][fn], acc[fm][fn], 0, 0, 0);                  \
        }                                                                       \
    } while (0)

    LOADH(hA, ks0);
    for (int t = ks0; t < ks1; t += 2) {
        TILE(t, hA, hB, 1);                      // t+1 <= ks1-1: always valid
        TILE(t + 1, hB, hA, (t + 2 < ks1));
    }
#undef TILE
#undef LOADH

    // ---- epilogue: 2 passes x 8KB LDS transpose, coalesced f32x4 stores ----
    const size_t zoff = (size_t)blockIdx.z * TOKENS * OUT;
#pragma unroll
    for (int h = 0; h < 2; ++h) {
        __syncthreads();                         // 1-wave: cheap, orders LDS
#pragma unroll
        for (int fp = 0; fp < 2; ++fp)           // fm = 2h + fp
#pragma unroll
            for (int fn = 0; fn < 4; ++fn)
#pragma unroll
                for (int r = 0; r < 4; ++r)
                    Pl[(fp * 16 + lg * 4 + r) * 64 + fn * 16 + lr] =
                        acc[2 * h + fp][fn][r];
        __syncthreads();
#pragma unroll
        for (int p = 0; p < 8; ++p) {
            int v = lane + p * 64;               // 0..511
            int row = v >> 4, cv = (v & 15) * 4;
            *(f32x4*)&P[zoff + (size_t)(n0 + h * 32 + row) * OUT + by * 64 + cv] =
                *(const f32x4*)&Pl[row * 64 + cv];
        }
    }
}

// ---------------- reduce 8 partial slices -> out ----------------
__global__ void reduce_split(const float* __restrict__ P, float* __restrict__ out,
                             int nvec) {
    int i = blockIdx.x * 256 + threadIdx.x;
    if (i >= nvec) return;
    const f32x4* Pv = (const f32x4*)P;
    f32x4 s = Pv[i];
#pragma unroll
    for (int z = 1; z < 8; ++z) s += Pv[(size_t)z * nvec + i];
    ((f32x4*)out)[i] = s;
}

extern "C" void kernel_launch(void* const* d_in, const int* in_sizes, int n_in,
                              void* d_out, int out_size, void* d_ws, size_t ws_size,
                              hipStream_t stream) {
    const float* x   = (const float*)d_in[0];
    const float* bw1 = (const float*)d_in[1];
    const float* sw1 = (const float*)d_in[2];
    const float* sc1 = (const float*)d_in[3];
    const float* bw2 = (const float*)d_in[4];
    const float* sw2 = (const float*)d_in[5];
    const float* sc2 = (const float*)d_in[6];
    float* out = (float*)d_out;

    char* ws = (char*)d_ws;
    __hip_bfloat16* W1  = (__hip_bfloat16*)ws;                   // 4MB
    __hip_bfloat16* W2f = (__hip_bfloat16*)(ws + (4ull << 20));  // 4MB fragment-major
    __hip_bfloat16* F1  = (__hip_bfloat16*)(ws + (8ull << 20));  // 32MB
    float*          Hb  = (float*)(ws + (40ull << 20));          // 32MB
    float*          Pp  = (float*)(ws + (72ull << 20));          // 64MB

    if (ws_size < (136ull << 20)) return;

    // fused: expand_x (8192 blocks) + prep W1 (1024) + prep W2f (1024)
    init_fused<<<10240, 256, 0, stream>>>(x, F1, bw1, sw1, sc1, W1, bw2, sw2, sc2, W2f);

    // GEMM1: (8192 x 2048) @ (1024 x 2048)^T + GELU -> Hb
    kan_gemm1<<<dim3(TOKENS / 128, D_HID / 128), 256, 0, stream>>>(F1, W1, Hb);

    // GEMM2: register-only, 4096 one-wave blocks -> 8 partial slices
    kan_gemm2<<<dim3(TOKENS / 64, D_IN / 64, 8), 64, 0, stream>>>(Hb, W2f, Pp);

    // Reduce partials -> out
    const int nvec = TOKENS * D_IN / 4;  // 524288
    reduce_split<<<(nvec + 255) / 256, 256, 0, stream>>>(Pp, out, nvec);
}

// Round 12
// 146.398 us; speedup vs baseline: 1.8715x; 1.8715x over previous
//
#include <hip/hip_runtime.h>
#include <hip/hip_bf16.h>
#include <math.h>

// KAN 2-layer forward, MI355X (gfx950) — round 12.
// Best-of assembly after r7-r11 ablations (r6 gemm2 beat 5 rewrites):
//   init_fused   : prep W1, prep W2 (row-major aug), expand x -> F1 (r7).
//   kan_gemm1    : r8 version (128x128, BK=64, counted vmcnt, setprio).
//                  FLAT grid + XCD swizzle: XCD = o-block -> 0.5MB W1 panel
//                  resident per XCD L2 (was: every XCD streams all 4MB).
//   kan_gemm2    : r6 body EXACT (BM=64 BN=256 BK=64 splitK=8, 4 blk/CU,
//                  single-buffer LDS, no atomics/fences) + GLL-before-features
//                  (r9) + setprio + FLAT grid XCD swizzle: XCD = z -> 512KB
//                  W2 k-slice resident per XCD L2.
//   reduce_split : sum 8 partial slices -> out.

typedef __attribute__((ext_vector_type(8))) short bf16x8;   // 8 x bf16
typedef __attribute__((ext_vector_type(4))) float f32x4;

#define TOKENS 8192
#define D_IN   256
#define D_HID  1024

// ---- exact uniform-cubic-B-spline features (closed form) ----
__device__ __forceinline__ void kan_features(float x, float f[8]) {
    f[0] = x * __builtin_amdgcn_rcpf(1.0f + __expf(-x));   // silu via v_rcp
    const float s = (x + 1.0f) * 1.5f + 3.0f;
    const float cf = floorf(s);
    const float u = s - cf;
    const int c = (int)cf;
    const float u2 = u * u, u3 = u2 * u;
    const float k6 = 1.0f / 6.0f;
    const float v3 = u3 * k6;
    const float v2 = (-3.0f * u3 + 3.0f * u2 + 3.0f * u + 1.0f) * k6;
    const float v1 = (3.0f * u3 - 6.0f * u2 + 4.0f) * k6;
    const float w1 = 1.0f - u;
    const float v0 = w1 * w1 * w1 * k6;
    const bool in = (s >= 0.0f) && (s < 9.0f);
#pragma unroll
    for (int j = 0; j < 6; ++j) {
        int d = c - j;
        float bv = (d == 0) ? v3 : (d == 1) ? v2 : (d == 2) ? v1 : (d == 3) ? v0 : 0.0f;
        f[1 + j] = in ? bv : 0.0f;
    }
    f[7] = 0.0f;
}

__device__ __forceinline__ void features_to_bf16(const float f[8], __hip_bfloat16 fb[8]) {
#pragma unroll
    for (int j = 0; j < 8; ++j) fb[j] = __float2bfloat16(f[j]);
}

// ---------------- fused init: expand_x (blocks 0..8191), prep W1, prep W2 ----------
__global__ void init_fused(const float* __restrict__ X, __hip_bfloat16* __restrict__ F,
                           const float* __restrict__ bw1, const float* __restrict__ sw1,
                           const float* __restrict__ sc1, __hip_bfloat16* __restrict__ W1,
                           const float* __restrict__ bw2, const float* __restrict__ sw2,
                           const float* __restrict__ sc2, __hip_bfloat16* __restrict__ W2) {
    const int b = blockIdx.x;
    if (b < 8192) {                          // expand x: 2M elements
        int idx = b * 256 + threadIdx.x;
        float f[8];
        kan_features(X[idx], f);
        __hip_bfloat16 fb[8];
        features_to_bf16(f, fb);
        *(bf16x8*)&F[(size_t)idx * 8] = *(bf16x8*)fb;
        return;
    }
    const bool w1 = (b < 9216);
    int idx = (w1 ? (b - 8192) : (b - 9216)) * 256 + threadIdx.x;   // < 262144
    const float* bw = w1 ? bw1 : bw2;
    const float* sw = w1 ? sw1 : sw2;
    const float* sc = w1 ? sc1 : sc2;
    __hip_bfloat16* Wo = w1 ? W1 : W2;
    float scl = sc[idx];
    __hip_bfloat16 row[8];
    row[0] = __float2bfloat16(bw[idx]);
#pragma unroll
    for (int j = 0; j < 6; ++j)
        row[1 + j] = __float2bfloat16(sw[idx * 6 + j] * scl);
    row[7] = __float2bfloat16(0.0f);
    *(bf16x8*)&Wo[(size_t)idx * 8] = *(bf16x8*)row;
}

#define GLL(src, dst) __builtin_amdgcn_global_load_lds(                         \
    (const __attribute__((address_space(1))) void*)(src),                       \
    (__attribute__((address_space(3))) void*)(dst), 16, 0, 0)

// ---------------- GEMM1: H = GELU(F1 @ W1^T), 128x128, BK=64, counted-vmcnt ----
// Flat grid 512; XCD = bid%8 = o-block: W1 panel (0.5MB) L2-resident per XCD.
__global__ __launch_bounds__(256, 2)
void kan_gemm1(const __hip_bfloat16* __restrict__ A,
               const __hip_bfloat16* __restrict__ W,
               float* __restrict__ H) {
    constexpr int K = D_IN * 8;            // 2048
    constexpr int NT = K / 64;             // 32 k-tiles
    __shared__ __hip_bfloat16 Al[2][128 * 64];
    __shared__ __hip_bfloat16 Bl[2][128 * 64];

    const int tid = threadIdx.x;
    const int wid = tid >> 6, lane = tid & 63;
    const int wm = wid >> 1, wn = wid & 1;
    const int lr = lane & 15, lg = lane >> 4;
    const int bid = blockIdx.x;
    const int o0 = (bid & 7) * 128;        // XCD-shared W1 panel
    const int n0 = (bid >> 3) * 128;

    int srow[4], sslot[4];
#pragma unroll
    for (int p = 0; p < 4; ++p) {
        int item = tid + p * 256;
        srow[p] = item >> 3;
        sslot[p] = (item & 7) ^ (srow[p] & 7);
    }
    int aoff[2][4], boff[2][4];
#pragma unroll
    for (int ks = 0; ks < 2; ++ks)
#pragma unroll
        for (int f = 0; f < 4; ++f) {
            int ar = wm * 64 + f * 16 + lr;
            int br = wn * 64 + f * 16 + lr;
            aoff[ks][f] = ar * 64 + (((ks * 4 + lg) ^ (ar & 7)) * 8);
            boff[ks][f] = br * 64 + (((ks * 4 + lg) ^ (br & 7)) * 8);
        }

    f32x4 acc[4][4] = {};

#define STG1(buf, kt)                                                           \
    do {                                                                        \
        _Pragma("unroll")                                                       \
        for (int p = 0; p < 4; ++p) {                                           \
            GLL(A + (size_t)(n0 + srow[p]) * K + (kt) * 64 + sslot[p] * 8,      \
                &Al[buf][(tid + p * 256) * 8]);                                 \
            GLL(W + (size_t)(o0 + srow[p]) * K + (kt) * 64 + sslot[p] * 8,      \
                &Bl[buf][(tid + p * 256) * 8]);                                 \
        }                                                                       \
    } while (0)

    STG1(0, 0);
    STG1(1, 1);
    for (int t = 0; t < NT; ++t) {
        const int cur = t & 1;
        asm volatile("s_waitcnt vmcnt(8)" ::: "memory");
        __builtin_amdgcn_s_barrier();
        __builtin_amdgcn_sched_barrier(0);
        __builtin_amdgcn_s_setprio(1);
#pragma unroll
        for (int ks = 0; ks < 2; ++ks) {
            bf16x8 af[4], bfr[4];
#pragma unroll
            for (int f = 0; f < 4; ++f) af[f] = *(const bf16x8*)&Al[cur][aoff[ks][f]];
#pragma unroll
            for (int f = 0; f < 4; ++f) bfr[f] = *(const bf16x8*)&Bl[cur][boff[ks][f]];
#pragma unroll
            for (int fm = 0; fm < 4; ++fm)
#pragma unroll
                for (int fn = 0; fn < 4; ++fn)
                    acc[fm][fn] = __builtin_amdgcn_mfma_f32_16x16x32_bf16(
                        af[fm], bfr[fn], acc[fm][fn], 0, 0, 0);
        }
        __builtin_amdgcn_s_setprio(0);
        asm volatile("s_waitcnt lgkmcnt(0)" ::: "memory");
        __builtin_amdgcn_s_barrier();
        __builtin_amdgcn_sched_barrier(0);
        const int kn = (t + 2 < NT) ? t + 2 : NT - 1;
        STG1(cur, kn);
    }
#undef STG1
#pragma unroll
    for (int fm = 0; fm < 4; ++fm) {
#pragma unroll
        for (int fn = 0; fn < 4; ++fn) {
            int col = o0 + wn * 64 + fn * 16 + lr;
#pragma unroll
            for (int r = 0; r < 4; ++r) {
                int row = n0 + wm * 64 + fm * 16 + lg * 4 + r;
                float v = acc[fm][fn][r];
                H[(size_t)row * D_HID + col] = 0.5f * v * (1.0f + erff(v * 0.70710678118f));
            }
        }
    }
}

// ---------------- GEMM2 (r6 body): P[z] = expand(h) @ W2^T slice ----------------
// BM=64, BN=256, BK=64, split-K=8, 4 blocks/CU, no atomics.
// Flat grid 1024; XCD = bid%8 = z: W2 k-slice (512KB) L2-resident per XCD.
__global__ __launch_bounds__(256, 4)
void kan_gemm2(const float* __restrict__ H,
               const __hip_bfloat16* __restrict__ W,
               float* __restrict__ P) {
    constexpr int OUT = D_IN, KD = D_HID * 8;   // 8192
    constexpr int NTT = KD / 64;                // 128 k-tiles
    __shared__ __hip_bfloat16 Al[64 * 64];      // 8KB
    __shared__ __hip_bfloat16 Bl[256 * 64];     // 32KB (reused as f32 in epi)

    const int tid = threadIdx.x;
    const int wid = tid >> 6, lane = tid & 63;
    const int lr = lane & 15, lg = lane >> 4;
    const int bid = blockIdx.x;
    const int z = bid & 7;                      // XCD-shared W2 k-slice
    const int n0 = (bid >> 3) * 64;

    const int per = NTT / 8;                    // 16
    const int ks0 = z * per, ks1 = ks0 + per;

    int srow[8], sslot[8];
#pragma unroll
    for (int p = 0; p < 8; ++p) {
        int item = tid + p * 256;
        srow[p] = item >> 3;
        sslot[p] = (item & 7) ^ (srow[p] & 7);
    }
    const int ar0 = tid >> 3, ac = tid & 7;
    const float* hp0 = H + (size_t)(n0 + ar0) * D_HID + ac;
    const float* hp1 = H + (size_t)(n0 + ar0 + 32) * D_HID + ac;
    const int aw0 = ar0 * 64 + ((ac ^ (ar0 & 7)) * 8);
    const int aw1 = (ar0 + 32) * 64 + ((ac ^ (ar0 & 7)) * 8);

    int aoff[2][4], boff[2][4];
#pragma unroll
    for (int ks = 0; ks < 2; ++ks)
#pragma unroll
        for (int f = 0; f < 4; ++f) {
            int ar = f * 16 + lr;
            int br = wid * 64 + f * 16 + lr;
            aoff[ks][f] = ar * 64 + (((ks * 4 + lg) ^ (ar & 7)) * 8);
            boff[ks][f] = br * 64 + (((ks * 4 + lg) ^ (br & 7)) * 8);
        }

    f32x4 acc[4][4] = {};

    float hv0 = hp0[(size_t)ks0 * 8];
    float hv1 = hp1[(size_t)ks0 * 8];

    for (int kt = ks0; kt < ks1; ++kt) {
        // B loads FIRST: 8 GLL fly under the feature VALU below (r9 ordering)
#pragma unroll
        for (int p = 0; p < 8; ++p)
            GLL(W + (size_t)srow[p] * KD + (size_t)kt * 64 + sslot[p] * 8,
                &Bl[(tid + p * 256) * 8]);
        float hc0 = hv0, hc1 = hv1;
        const int knext = (kt + 1 < ks1) ? kt + 1 : ks1 - 1;
        hv0 = hp0[(size_t)knext * 8];
        hv1 = hp1[(size_t)knext * 8];
        {
            float ff[8]; __hip_bfloat16 fb[8];
            kan_features(hc0, ff); features_to_bf16(ff, fb);
            *(bf16x8*)&Al[aw0] = *(bf16x8*)fb;
            kan_features(hc1, ff); features_to_bf16(ff, fb);
            *(bf16x8*)&Al[aw1] = *(bf16x8*)fb;
        }
        __syncthreads();
        __builtin_amdgcn_s_setprio(1);
#pragma unroll
        for (int ks = 0; ks < 2; ++ks) {
            bf16x8 af[4], bfr[4];
#pragma unroll
            for (int f = 0; f < 4; ++f) af[f] = *(const bf16x8*)&Al[aoff[ks][f]];
#pragma unroll
            for (int f = 0; f < 4; ++f) bfr[f] = *(const bf16x8*)&Bl[boff[ks][f]];
#pragma unroll
            for (int fm = 0; fm < 4; ++fm)
#pragma unroll
                for (int fn = 0; fn < 4; ++fn)
                    acc[fm][fn] = __builtin_amdgcn_mfma_f32_16x16x32_bf16(
                        af[fm], bfr[fn], acc[fm][fn], 0, 0, 0);
        }
        __builtin_amdgcn_s_setprio(0);
        __syncthreads();
    }

    // ---- epilogue: transpose via LDS (reuse Bl), coalesced f32x4 partial stores ----
    float* Pl = (float*)Bl;                      // 64 x 128 f32 = 32KB
    const size_t zoff = (size_t)z * TOKENS * OUT;
#pragma unroll
    for (int h = 0; h < 2; ++h) {
        __syncthreads();
        if ((wid >> 1) == h) {
#pragma unroll
            for (int fm = 0; fm < 4; ++fm)
#pragma unroll
                for (int fn = 0; fn < 4; ++fn) {
                    int c = (wid & 1) * 64 + fn * 16 + lr;
#pragma unroll
                    for (int r = 0; r < 4; ++r)
                        Pl[(fm * 16 + lg * 4 + r) * 128 + c] = acc[fm][fn][r];
                }
        }
        __syncthreads();
#pragma unroll
        for (int q = 0; q < 8; ++q) {
            int v = tid + q * 256;               // 0..2047
            int row = v >> 5, cv = (v & 31) * 4;
            *(f32x4*)&P[zoff + (size_t)(n0 + row) * OUT + h * 128 + cv] =
                *(const f32x4*)&Pl[row * 128 + cv];
        }
    }
}

// ---------------- reduce 8 partial slices -> out ----------------
__global__ void reduce_split(const float* __restrict__ P, float* __restrict__ out,
                             int nvec) {
    int i = blockIdx.x * 256 + threadIdx.x;
    if (i >= nvec) return;
    const f32x4* Pv = (const f32x4*)P;
    f32x4 s = Pv[i];
#pragma unroll
    for (int z = 1; z < 8; ++z) s += Pv[(size_t)z * nvec + i];
    ((f32x4*)out)[i] = s;
}

extern "C" void kernel_launch(void* const* d_in, const int* in_sizes, int n_in,
                              void* d_out, int out_size, void* d_ws, size_t ws_size,
                              hipStream_t stream) {
    const float* x   = (const float*)d_in[0];
    const float* bw1 = (const float*)d_in[1];
    const float* sw1 = (const float*)d_in[2];
    const float* sc1 = (const float*)d_in[3];
    const float* bw2 = (const float*)d_in[4];
    const float* sw2 = (const float*)d_in[5];
    const float* sc2 = (const float*)d_in[6];
    float* out = (float*)d_out;

    char* ws = (char*)d_ws;
    __hip_bfloat16* W1 = (__hip_bfloat16*)ws;                   // 4MB
    __hip_bfloat16* W2 = (__hip_bfloat16*)(ws + (4ull << 20));  // 4MB
    __hip_bfloat16* F1 = (__hip_bfloat16*)(ws + (8ull << 20));  // 32MB
    float*          Hb = (float*)(ws + (40ull << 20));          // 32MB
    float*          Pp = (float*)(ws + (72ull << 20));          // 64MB

    if (ws_size < (136ull << 20)) return;

    // fused: expand_x (8192 blocks) + prep W1 (1024) + prep W2 (1024)
    init_fused<<<10240, 256, 0, stream>>>(x, F1, bw1, sw1, sc1, W1, bw2, sw2, sc2, W2);

    // GEMM1: flat grid 512, XCD = o-block
    kan_gemm1<<<512, 256, 0, stream>>>(F1, W1, Hb);

    // GEMM2: flat grid 1024, XCD = z (W2 k-slice per XCD)
    kan_gemm2<<<1024, 256, 0, stream>>>(Hb, W2, Pp);

    // Reduce partials -> out
    const int nvec = TOKENS * D_IN / 4;  // 524288
    reduce_split<<<(nvec + 255) / 256, 256, 0, stream>>>(Pp, out, nvec);
}

// Round 13
// 136.655 us; speedup vs baseline: 2.0049x; 1.0713x over previous
//
#include <hip/hip_runtime.h>
#include <hip/hip_bf16.h>
#include <math.h>

// KAN 2-layer forward, MI355X (gfx950) — round 13.
//   init_fused   : prep W1, prep W2 (row-major aug), expand x -> F1.
//   kan_gemm1    : r8-proven (128x128, BK=64, counted vmcnt, setprio, 2D grid)
//                  but H stored BF16 (halves H write; err << threshold).
//   kan_gemm2    : r6 body scaled up: BM=128 (512 thr, 8 waves 2x4), BN=256,
//                  BK=64, split-K=8 -> 512 blocks = 2/CU = 16 waves/CU (same
//                  TLP as r6) with HALF the W2 re-staging and 2x MFMA per
//                  barrier-drain. Single-buffer LDS, 2 barriers/tile, no
//                  atomics/fences/setprio (r6 ordering kept verbatim).
//   reduce_split : sum 8 partial slices -> out.
// Ablation ledger: r6 gemm2(69us) beat counted-vmcnt(158), BK32(87), BN128(98),
// reg-only(212), fused-reduce+fence(229), XCD-swizzle(71.5). This round scales
// r6's winning regime instead of restructuring it.

typedef __attribute__((ext_vector_type(8))) short bf16x8;   // 8 x bf16
typedef __attribute__((ext_vector_type(4))) float f32x4;

#define TOKENS 8192
#define D_IN   256
#define D_HID  1024

// ---- exact uniform-cubic-B-spline features (closed form) ----
__device__ __forceinline__ void kan_features(float x, float f[8]) {
    f[0] = x * __builtin_amdgcn_rcpf(1.0f + __expf(-x));   // silu via v_rcp
    const float s = (x + 1.0f) * 1.5f + 3.0f;
    const float cf = floorf(s);
    const float u = s - cf;
    const int c = (int)cf;
    const float u2 = u * u, u3 = u2 * u;
    const float k6 = 1.0f / 6.0f;
    const float v3 = u3 * k6;
    const float v2 = (-3.0f * u3 + 3.0f * u2 + 3.0f * u + 1.0f) * k6;
    const float v1 = (3.0f * u3 - 6.0f * u2 + 4.0f) * k6;
    const float w1 = 1.0f - u;
    const float v0 = w1 * w1 * w1 * k6;
    const bool in = (s >= 0.0f) && (s < 9.0f);
#pragma unroll
    for (int j = 0; j < 6; ++j) {
        int d = c - j;
        float bv = (d == 0) ? v3 : (d == 1) ? v2 : (d == 2) ? v1 : (d == 3) ? v0 : 0.0f;
        f[1 + j] = in ? bv : 0.0f;
    }
    f[7] = 0.0f;
}

__device__ __forceinline__ void features_to_bf16(const float f[8], __hip_bfloat16 fb[8]) {
#pragma unroll
    for (int j = 0; j < 8; ++j) fb[j] = __float2bfloat16(f[j]);
}

// ---------------- fused init: expand_x (blocks 0..8191), prep W1, prep W2 ----------
__global__ void init_fused(const float* __restrict__ X, __hip_bfloat16* __restrict__ F,
                           const float* __restrict__ bw1, const float* __restrict__ sw1,
                           const float* __restrict__ sc1, __hip_bfloat16* __restrict__ W1,
                           const float* __restrict__ bw2, const float* __restrict__ sw2,
                           const float* __restrict__ sc2, __hip_bfloat16* __restrict__ W2) {
    const int b = blockIdx.x;
    if (b < 8192) {                          // expand x: 2M elements
        int idx = b * 256 + threadIdx.x;
        float f[8];
        kan_features(X[idx], f);
        __hip_bfloat16 fb[8];
        features_to_bf16(f, fb);
        *(bf16x8*)&F[(size_t)idx * 8] = *(bf16x8*)fb;
        return;
    }
    const bool w1 = (b < 9216);
    int idx = (w1 ? (b - 8192) : (b - 9216)) * 256 + threadIdx.x;   // < 262144
    const float* bw = w1 ? bw1 : bw2;
    const float* sw = w1 ? sw1 : sw2;
    const float* sc = w1 ? sc1 : sc2;
    __hip_bfloat16* Wo = w1 ? W1 : W2;
    float scl = sc[idx];
    __hip_bfloat16 row[8];
    row[0] = __float2bfloat16(bw[idx]);
#pragma unroll
    for (int j = 0; j < 6; ++j)
        row[1 + j] = __float2bfloat16(sw[idx * 6 + j] * scl);
    row[7] = __float2bfloat16(0.0f);
    *(bf16x8*)&Wo[(size_t)idx * 8] = *(bf16x8*)row;
}

#define GLL(src, dst) __builtin_amdgcn_global_load_lds(                         \
    (const __attribute__((address_space(1))) void*)(src),                       \
    (__attribute__((address_space(3))) void*)(dst), 16, 0, 0)

// ---------------- GEMM1: H = bf16(GELU(F1 @ W1^T)), 128x128, BK=64 ----------------
__global__ __launch_bounds__(256, 2)
void kan_gemm1(const __hip_bfloat16* __restrict__ A,
               const __hip_bfloat16* __restrict__ W,
               __hip_bfloat16* __restrict__ H) {
    constexpr int K = D_IN * 8;            // 2048
    constexpr int NT = K / 64;             // 32 k-tiles
    __shared__ __hip_bfloat16 Al[2][128 * 64];
    __shared__ __hip_bfloat16 Bl[2][128 * 64];

    const int tid = threadIdx.x;
    const int wid = tid >> 6, lane = tid & 63;
    const int wm = wid >> 1, wn = wid & 1;
    const int lr = lane & 15, lg = lane >> 4;
    const int n0 = blockIdx.x * 128, o0 = blockIdx.y * 128;

    int srow[4], sslot[4];
#pragma unroll
    for (int p = 0; p < 4; ++p) {
        int item = tid + p * 256;
        srow[p] = item >> 3;
        sslot[p] = (item & 7) ^ (srow[p] & 7);
    }
    int aoff[2][4], boff[2][4];
#pragma unroll
    for (int ks = 0; ks < 2; ++ks)
#pragma unroll
        for (int f = 0; f < 4; ++f) {
            int ar = wm * 64 + f * 16 + lr;
            int br = wn * 64 + f * 16 + lr;
            aoff[ks][f] = ar * 64 + (((ks * 4 + lg) ^ (ar & 7)) * 8);
            boff[ks][f] = br * 64 + (((ks * 4 + lg) ^ (br & 7)) * 8);
        }

    f32x4 acc[4][4] = {};

#define STG1(buf, kt)                                                           \
    do {                                                                        \
        _Pragma("unroll")                                                       \
        for (int p = 0; p < 4; ++p) {                                           \
            GLL(A + (size_t)(n0 + srow[p]) * K + (kt) * 64 + sslot[p] * 8,      \
                &Al[buf][(tid + p * 256) * 8]);                                 \
            GLL(W + (size_t)(o0 + srow[p]) * K + (kt) * 64 + sslot[p] * 8,      \
                &Bl[buf][(tid + p * 256) * 8]);                                 \
        }                                                                       \
    } while (0)

    STG1(0, 0);
    STG1(1, 1);
    for (int t = 0; t < NT; ++t) {
        const int cur = t & 1;
        asm volatile("s_waitcnt vmcnt(8)" ::: "memory");
        __builtin_amdgcn_s_barrier();
        __builtin_amdgcn_sched_barrier(0);
        __builtin_amdgcn_s_setprio(1);
#pragma unroll
        for (int ks = 0; ks < 2; ++ks) {
            bf16x8 af[4], bfr[4];
#pragma unroll
            for (int f = 0; f < 4; ++f) af[f] = *(const bf16x8*)&Al[cur][aoff[ks][f]];
#pragma unroll
            for (int f = 0; f < 4; ++f) bfr[f] = *(const bf16x8*)&Bl[cur][boff[ks][f]];
#pragma unroll
            for (int fm = 0; fm < 4; ++fm)
#pragma unroll
                for (int fn = 0; fn < 4; ++fn)
                    acc[fm][fn] = __builtin_amdgcn_mfma_f32_16x16x32_bf16(
                        af[fm], bfr[fn], acc[fm][fn], 0, 0, 0);
        }
        __builtin_amdgcn_s_setprio(0);
        asm volatile("s_waitcnt lgkmcnt(0)" ::: "memory");
        __builtin_amdgcn_s_barrier();
        __builtin_amdgcn_sched_barrier(0);
        const int kn = (t + 2 < NT) ? t + 2 : NT - 1;
        STG1(cur, kn);
    }
#undef STG1
#pragma unroll
    for (int fm = 0; fm < 4; ++fm) {
#pragma unroll
        for (int fn = 0; fn < 4; ++fn) {
            int col = o0 + wn * 64 + fn * 16 + lr;
#pragma unroll
            for (int r = 0; r < 4; ++r) {
                int row = n0 + wm * 64 + fm * 16 + lg * 4 + r;
                float v = acc[fm][fn][r];
                float g = 0.5f * v * (1.0f + erff(v * 0.70710678118f));
                H[(size_t)row * D_HID + col] = __float2bfloat16(g);
            }
        }
    }
}

// ---------------- GEMM2: r6 body at BM=128, 512 threads (8 waves 2x4) ----------------
// BM=128, BN=256, BK=64, split-K=8 -> 512 blocks = 2/CU = 16 waves/CU.
__global__ __launch_bounds__(512, 2)
void kan_gemm2(const __hip_bfloat16* __restrict__ H,
               const __hip_bfloat16* __restrict__ W,
               float* __restrict__ P) {
    constexpr int OUT = D_IN, KD = D_HID * 8;   // 8192
    constexpr int NTT = KD / 64;                // 128 k-tiles
    __shared__ __hip_bfloat16 Al[128 * 64];     // 16KB
    __shared__ __hip_bfloat16 Bl[256 * 64];     // 32KB (reused as f32 in epi)

    const int tid = threadIdx.x;
    const int wid = tid >> 6, lane = tid & 63;
    const int wm = wid >> 2, wn = wid & 3;      // 2x4 waves: 64-row x 64-col tiles
    const int lr = lane & 15, lg = lane >> 4;
    const int n0 = blockIdx.x * 128;

    const int per = NTT / 8;                    // 16
    const int ks0 = blockIdx.z * per, ks1 = ks0 + per;

    // B staging: 4 items/thread (256 rows x 8 slots = 2048), swizzled source slot
    int srow[4], sslot[4];
#pragma unroll
    for (int p = 0; p < 4; ++p) {
        int item = tid + p * 512;
        srow[p] = item >> 3;
        sslot[p] = (item & 7) ^ (srow[p] & 7);
    }
    // A features: 2 items/thread: rows ar0, ar0+64; h channel-in-tile = tid&7
    const int ar0 = tid >> 3, ac = tid & 7;
    const __hip_bfloat16* hp0 = H + (size_t)(n0 + ar0) * D_HID + ac;
    const __hip_bfloat16* hp1 = H + (size_t)(n0 + ar0 + 64) * D_HID + ac;
    const int aw0 = ar0 * 64 + ((ac ^ (ar0 & 7)) * 8);
    const int aw1 = (ar0 + 64) * 64 + ((ac ^ (ar0 & 7)) * 8);

    int aoff[2][4], boff[2][4];
#pragma unroll
    for (int ks = 0; ks < 2; ++ks)
#pragma unroll
        for (int f = 0; f < 4; ++f) {
            int ar = wm * 64 + f * 16 + lr;
            int br = wn * 64 + f * 16 + lr;
            aoff[ks][f] = ar * 64 + (((ks * 4 + lg) ^ (ar & 7)) * 8);
            boff[ks][f] = br * 64 + (((ks * 4 + lg) ^ (br & 7)) * 8);
        }

    f32x4 acc[4][4] = {};

    float hv0 = __bfloat162float(hp0[(size_t)ks0 * 8]);
    float hv1 = __bfloat162float(hp1[(size_t)ks0 * 8]);

    for (int kt = ks0; kt < ks1; ++kt) {
        float hc0 = hv0, hc1 = hv1;
        const int knext = (kt + 1 < ks1) ? kt + 1 : ks1 - 1;
        hv0 = __bfloat162float(hp0[(size_t)knext * 8]);
        hv1 = __bfloat162float(hp1[(size_t)knext * 8]);
        {   // features -> swizzled LDS (r6 ordering: features, then GLL, then sync)
            float ff[8]; __hip_bfloat16 fb[8];
            kan_features(hc0, ff); features_to_bf16(ff, fb);
            *(bf16x8*)&Al[aw0] = *(bf16x8*)fb;
            kan_features(hc1, ff); features_to_bf16(ff, fb);
            *(bf16x8*)&Al[aw1] = *(bf16x8*)fb;
        }
#pragma unroll
        for (int p = 0; p < 4; ++p)
            GLL(W + (size_t)srow[p] * KD + (size_t)kt * 64 + sslot[p] * 8,
                &Bl[(tid + p * 512) * 8]);
        __syncthreads();
#pragma unroll
        for (int ks = 0; ks < 2; ++ks) {
            bf16x8 af[4], bfr[4];
#pragma unroll
            for (int f = 0; f < 4; ++f) af[f] = *(const bf16x8*)&Al[aoff[ks][f]];
#pragma unroll
            for (int f = 0; f < 4; ++f) bfr[f] = *(const bf16x8*)&Bl[boff[ks][f]];
#pragma unroll
            for (int fm = 0; fm < 4; ++fm)
#pragma unroll
                for (int fn = 0; fn < 4; ++fn)
                    acc[fm][fn] = __builtin_amdgcn_mfma_f32_16x16x32_bf16(
                        af[fm], bfr[fn], acc[fm][fn], 0, 0, 0);
        }
        __syncthreads();
    }

    // ---- epilogue: 4 quarter-passes (32 rows x 256 cols f32 = 32KB in Bl) ----
    float* Pl = (float*)Bl;
    const size_t zoff = (size_t)blockIdx.z * TOKENS * OUT;
#pragma unroll
    for (int q = 0; q < 4; ++q) {
        __syncthreads();
        if (wm == (q >> 1)) {
#pragma unroll
            for (int fp = 0; fp < 2; ++fp) {     // fm = (q&1)*2 + fp
                int fm = (q & 1) * 2 + fp;
#pragma unroll
                for (int fn = 0; fn < 4; ++fn) {
                    int c = wn * 64 + fn * 16 + lr;
#pragma unroll
                    for (int r = 0; r < 4; ++r)
                        Pl[(fp * 16 + lg * 4 + r) * 256 + c] = acc[fm][fn][r];
                }
            }
        }
        __syncthreads();
#pragma unroll
        for (int p = 0; p < 4; ++p) {
            int v = tid + p * 512;               // 0..2047
            int row = v >> 6, cv = (v & 63) * 4;
            *(f32x4*)&P[zoff + (size_t)(n0 + q * 32 + row) * OUT + cv] =
                *(const f32x4*)&Pl[row * 256 + cv];
        }
    }
}

// ---------------- reduce 8 partial slices -> out ----------------
__global__ void reduce_split(const float* __restrict__ P, float* __restrict__ out,
                             int nvec) {
    int i = blockIdx.x * 256 + threadIdx.x;
    if (i >= nvec) return;
    const f32x4* Pv = (const f32x4*)P;
    f32x4 s = Pv[i];
#pragma unroll
    for (int z = 1; z < 8; ++z) s += Pv[(size_t)z * nvec + i];
    ((f32x4*)out)[i] = s;
}

extern "C" void kernel_launch(void* const* d_in, const int* in_sizes, int n_in,
                              void* d_out, int out_size, void* d_ws, size_t ws_size,
                              hipStream_t stream) {
    const float* x   = (const float*)d_in[0];
    const float* bw1 = (const float*)d_in[1];
    const float* sw1 = (const float*)d_in[2];
    const float* sc1 = (const float*)d_in[3];
    const float* bw2 = (const float*)d_in[4];
    const float* sw2 = (const float*)d_in[5];
    const float* sc2 = (const float*)d_in[6];
    float* out = (float*)d_out;

    char* ws = (char*)d_ws;
    __hip_bfloat16* W1 = (__hip_bfloat16*)ws;                   // 4MB
    __hip_bfloat16* W2 = (__hip_bfloat16*)(ws + (4ull << 20));  // 4MB
    __hip_bfloat16* F1 = (__hip_bfloat16*)(ws + (8ull << 20));  // 32MB
    __hip_bfloat16* Hb = (__hip_bfloat16*)(ws + (40ull << 20)); // 16MB (bf16 now)
    float*          Pp = (float*)(ws + (72ull << 20));          // 64MB

    if (ws_size < (136ull << 20)) return;

    // fused: expand_x (8192 blocks) + prep W1 (1024) + prep W2 (1024)
    init_fused<<<10240, 256, 0, stream>>>(x, F1, bw1, sw1, sc1, W1, bw2, sw2, sc2, W2);

    // GEMM1: (8192 x 2048) @ (1024 x 2048)^T + GELU -> Hb (bf16)
    kan_gemm1<<<dim3(TOKENS / 128, D_HID / 128), 256, 0, stream>>>(F1, W1, Hb);

    // GEMM2: expand(Hb) @ (256 x 8192)^T -> 8 partial slices
    kan_gemm2<<<dim3(TOKENS / 128, 1, 8), 512, 0, stream>>>(Hb, W2, Pp);

    // Reduce partials -> out
    const int nvec = TOKENS * D_IN / 4;  // 524288
    reduce_split<<<(nvec + 255) / 256, 256, 0, stream>>>(Pp, out, nvec);
}